// Round 14
// baseline (185.210 us; speedup 1.0000x reference)
//
#include <hip/hip_runtime.h>

// y[n] = beta0 + sum_c X[n,c]*(beta[c] + Z[n,c]),  Z = X @ triu(Theta,1)
// R14 = R13 (in-GEMM f32->bf16 A staging, no conv_x) + R11's BK=64 (half the
// barrier/drain events, 2x MFMA per stage) + 3-bit quad-XOR swizzle
// (A: write-side q^(row&7); B: pre-swizzled Q^(c&7) in conv_theta) + R12's
// transposed-MFMA D[c,n] epilogue reading f32 X row-contiguously.
// 128x128 tile, 8 waves, dbuf 64 KB, XCD swizzle + heavy-first LPT. 2 launches.

typedef __bf16 bf16_t;
typedef bf16_t bf16x8 __attribute__((ext_vector_type(8)));
typedef float f32x4 __attribute__((ext_vector_type(4)));
typedef unsigned short u16;
typedef u16 u16x4 __attribute__((ext_vector_type(4)));
typedef u16 u16x8 __attribute__((ext_vector_type(8)));

#define N_ROWS 65536
#define P_DIM  1024
#define BM 128
#define BN 128
#define BK 64

static __device__ __forceinline__ u16 f2bf(float f) {
  unsigned u = __builtin_bit_cast(unsigned, f);
  u += 0x7FFFu + ((u >> 16) & 1u);   // round-to-nearest-even
  return (u16)(u >> 16);
}

// global(16B/lane, per-lane src) -> LDS direct (wave-uniform dest + lane*16).
static __device__ __forceinline__ void gload16(const void* g, void* lds_base) {
  __builtin_amdgcn_global_load_lds(
      (const __attribute__((address_space(1))) unsigned char*)g,
      (__attribute__((address_space(3))) unsigned char*)lds_base, 16, 0, 0);
}

__global__ void __launch_bounds__(256)
init_y(float* __restrict__ y, const float* __restrict__ beta0) {
  int i = blockIdx.x * blockDim.x + threadIdx.x;
  if (i < N_ROWS) y[i] = beta0[0];
}

// ---- conv: Tt[c][q'] = triu-masked bf16 Theta^T quad q, stored at
// q' = q ^ (c&7) (segment-local within each 8-quad / 64-k group; BK=64
// tiles are 64-aligned so the involution stays in-tile). Also inits y.
__global__ void __launch_bounds__(128)
conv_theta(const float* __restrict__ Theta, u16* __restrict__ Tt,
           float* __restrict__ y, const float* __restrict__ beta0) {
  __shared__ float tile[32][33];
  const int tid = threadIdx.x;         // 0..127
  const int tg  = (blockIdx.y * gridDim.x + blockIdx.x) * 128 + tid;
  if (tg < N_ROWS) y[tg] = beta0[0];

  const int k0  = blockIdx.x * 32;
  const int c0  = blockIdx.y * 32;
  {
    const int tx = tid & 31;           // c within tile
    const int rb = tid >> 5;           // 0..3
    #pragma unroll
    for (int i = 0; i < 8; ++i) {
      int kl = rb * 8 + i;
      tile[kl][tx] = Theta[(size_t)(k0 + kl) * P_DIM + c0 + tx];
    }
  }
  __syncthreads();
  {
    const int cl = tid >> 2;           // 0..31
    const int qt = tid & 3;            // quad within this 32-k tile
    const int c  = c0 + cl;
    const int Q  = blockIdx.x * 4 + qt;  // global quad 0..127
    u16x8 w;
    #pragma unroll
    for (int e = 0; e < 8; ++e) {
      int k = Q * 8 + e;
      float v = tile[qt * 8 + e][cl];
      w[e] = (k < c) ? f2bf(v) : (u16)0;
    }
    *(u16x8*)(Tt + (size_t)c * P_DIM + (size_t)((Q ^ (c & 7)) * 8)) = w;
  }
}

// ---- main GEMM + fused epilogue: 128x128, 8 waves, BK=64 dbuf,
// A reg-staged f32->bf16 (write-swizzled), B gload16 (pre-swizzled) ----
__global__ void __launch_bounds__(512)
gemm_r14(const float* __restrict__ X, const u16* __restrict__ Tt,
         const float* __restrict__ beta, float* __restrict__ y)
{
  // per buffer: A [128][64] u16 at 0..8191, B [128][64] u16 at 8192..16383
  __shared__ __align__(16) u16 L[2][16384];   // 64 KB total

  // XCD swizzle + heavy-first LPT: consecutive bids on one XCD share bm
  // (A-panel L2 reuse), bn descending (long-K first).
  const int nwg = (N_ROWS / BM) * (P_DIM / BN);    // 4096
  const int swz = (blockIdx.x & 7) * (nwg / 8) + (blockIdx.x >> 3);
  const int bn  = 7 - (swz & 7);
  const int bm  = swz >> 3;
  const int c0  = bn * BN;
  const int m0  = bm * BM;
  const int nkt = (bn + 1) * 2;        // K-steps of 64: 2..16

  const int tid  = threadIdx.x;
  const int lane = tid & 63;
  const int wid  = tid >> 6;           // 0..7
  const int wm   = wid >> 1;           // 0..3  (32-row strip)
  const int wn   = wid & 1;            // 0..1  (64-col half)
  const int l15  = lane & 15;
  const int lg   = lane >> 4;

  // ---- A staging (reg-staged): thread -> row ar, 16-f32 group ap ----
  // covers quads q = 2ap, 2ap+1; stored at position q ^ (ar&7).
  const int ar  = tid >> 2;            // 0..127
  const int ap  = tid & 3;             // 16-f32 group
  const int aq0 = ((2 * ap)     ^ (ar & 7)) * 8;   // u16 offsets in row
  const int aq1 = ((2 * ap + 1) ^ (ar & 7)) * 8;

  // ---- B staging: chunk = 8 rows x 64 k (1 KB); lane -> row l>>3, quad l&7 ----
  const int srow = lane >> 3;          // 0..7
  const int sq   = (lane & 7) * 8;     // source quad offset (pre-swizzled Tt)

  f32x4 acc[2][4];
  #pragma unroll
  for (int i = 0; i < 2; ++i)
    #pragma unroll
    for (int j = 0; j < 4; ++j)
      acc[i][j] = (f32x4)0.0f;

  f32x4 av0, av1, av2, av3;   // A staging registers (16 f32)

  #define STAGE_A_LOAD(t_)                                                      \
    {                                                                           \
      const float* s_ = X + (size_t)(m0 + ar) * P_DIM + (t_) * BK + ap * 16;    \
      av0 = ((const f32x4*)s_)[0];                                              \
      av1 = ((const f32x4*)s_)[1];                                              \
      av2 = ((const f32x4*)s_)[2];                                              \
      av3 = ((const f32x4*)s_)[3];                                              \
    }
  #define STAGE_A_WRITE(buf_)                                                   \
    {                                                                           \
      u16x8 w0_, w1_;                                                           \
      _Pragma("unroll")                                                         \
      for (int j = 0; j < 4; ++j) {                                             \
        w0_[j] = f2bf(av0[j]); w0_[j + 4] = f2bf(av1[j]);                       \
        w1_[j] = f2bf(av2[j]); w1_[j + 4] = f2bf(av3[j]);                       \
      }                                                                         \
      *(u16x8*)&L[buf_][ar * 64 + aq0] = w0_;                                   \
      *(u16x8*)&L[buf_][ar * 64 + aq1] = w1_;                                   \
    }
  #define STAGE_B(buf_, t_)                                                     \
    {                                                                           \
      _Pragma("unroll")                                                         \
      for (int q = 0; q < 2; ++q) {                                             \
        const int ch_ = wid * 2 + q;                                            \
        gload16(Tt + (size_t)(c0 + ch_ * 8 + srow) * P_DIM + (t_) * BK + sq,    \
                &L[buf_][8192 + ch_ * 512]);                                    \
      }                                                                         \
    }

  // prologue: tile 0
  STAGE_A_LOAD(0)
  STAGE_B(0, 0)
  asm volatile("s_waitcnt vmcnt(0)" ::: "memory");
  __builtin_amdgcn_sched_barrier(0);
  STAGE_A_WRITE(0)
  asm volatile("s_waitcnt lgkmcnt(0)" ::: "memory");
  __builtin_amdgcn_sched_barrier(0);
  __builtin_amdgcn_s_barrier();
  __builtin_amdgcn_sched_barrier(0);

  for (int t = 0; t < nkt; ++t) {
    const int cur = t & 1;
    const bool pre = (t + 1 < nkt);
    // issue next-tile loads EARLY: global latency hides under frags+MFMA
    if (pre) { STAGE_A_LOAD(t + 1) STAGE_B(cur ^ 1, t + 1) }

    // fragment ds_reads — 3-bit quad-XOR -> 2 lanes/bank (free)
    bf16x8 af[2][2], bfr[2][4];
    #pragma unroll
    for (int kk = 0; kk < 2; ++kk) {
      #pragma unroll
      for (int mi = 0; mi < 2; ++mi) {
        const int rw = wm * 32 + mi * 16 + l15;
        u16x8 v = *(const u16x8*)&L[cur][rw * 64 + ((kk * 4 + lg) ^ (rw & 7)) * 8];
        af[kk][mi] = __builtin_bit_cast(bf16x8, v);
      }
      #pragma unroll
      for (int ni = 0; ni < 4; ++ni) {
        const int cl = wn * 64 + ni * 16 + l15;
        u16x8 v = *(const u16x8*)&L[cur][8192 + cl * 64 + ((kk * 4 + lg) ^ (cl & 7)) * 8];
        bfr[kk][ni] = __builtin_bit_cast(bf16x8, v);
      }
    }

    // TRANSPOSED MFMA: D[c,n], lane l15 = n (row), lg*4+r = c
    __builtin_amdgcn_s_setprio(1);
    #pragma unroll
    for (int kk = 0; kk < 2; ++kk)
      #pragma unroll
      for (int mi = 0; mi < 2; ++mi)
        #pragma unroll
        for (int ni = 0; ni < 4; ++ni)
          acc[mi][ni] = __builtin_amdgcn_mfma_f32_16x16x32_bf16(bfr[kk][ni], af[kk][mi], acc[mi][ni], 0, 0, 0);
    __builtin_amdgcn_s_setprio(0);

    if (pre) {
      asm volatile("s_waitcnt vmcnt(0)" ::: "memory");   // av regs + B gload landed
      __builtin_amdgcn_sched_barrier(0);
      STAGE_A_WRITE(cur ^ 1)
    }
    asm volatile("s_waitcnt lgkmcnt(0)" ::: "memory");   // my ds_writes visible
    __builtin_amdgcn_sched_barrier(0);
    __builtin_amdgcn_s_barrier();
    __builtin_amdgcn_sched_barrier(0);
  }
  #undef STAGE_A_LOAD
  #undef STAGE_A_WRITE
  #undef STAGE_B

  // ---- epilogue: y_partial[row] = sum_c (Z[row,c] + beta[c]) * X[row,c] ----
  // D[c,n]: n = row = base+l15, c = c0 + wn*64 + ni*16 + lg*4 + r. X read f32.
  float ysum[2];
  ysum[0] = 0.0f; ysum[1] = 0.0f;

  #pragma unroll
  for (int mi = 0; mi < 2; ++mi) {
    const int row = m0 + wm * 32 + mi * 16 + l15;
    const float* xr = X + (size_t)row * P_DIM;
    #pragma unroll
    for (int ni = 0; ni < 4; ++ni) {
      const int cb = c0 + wn * 64 + ni * 16 + lg * 4;   // 4 consecutive cols
      f32x4 xw = *(const f32x4*)(xr + cb);
      f32x4 bv = *(const f32x4*)(beta + cb);
      #pragma unroll
      for (int r = 0; r < 4; ++r)
        ysum[mi] += (acc[mi][ni][r] + bv[r]) * xw[r];
    }
  }

  #pragma unroll
  for (int mi = 0; mi < 2; ++mi) {
    ysum[mi] += __shfl_xor(ysum[mi], 16);
    ysum[mi] += __shfl_xor(ysum[mi], 32);
  }
  if (lane < 16) {
    #pragma unroll
    for (int mi = 0; mi < 2; ++mi)
      atomicAdd(&y[m0 + wm * 32 + mi * 16 + l15], ysum[mi]);
  }
}

// ================= fallback (R1 kernel, 128x128) if ws too small =================
#define LDT 40
__global__ void __launch_bounds__(256)
fused_quad_fallback(const float* __restrict__ X, const float* __restrict__ beta,
                    const float* __restrict__ Theta, float* __restrict__ y)
{
  __shared__ __align__(16) u16 Alds[128 * LDT];
  __shared__ __align__(16) u16 Blds[128 * LDT];

  const int bid = blockIdx.x;
  const int bn  = bid & 7;
  const int bm  = bid >> 3;
  const int c0  = bn * 128;
  const int m0  = bm * 128;
  const int nkt = (bn + 1) * 4;

  const int tid  = threadIdx.x;
  const int lane = tid & 63;
  const int wid  = tid >> 6;
  const int wm   = wid >> 1;
  const int wn   = wid & 1;
  const int l15  = lane & 15;
  const int lg   = lane >> 4;

  f32x4 acc[4][4];
  #pragma unroll
  for (int i = 0; i < 4; ++i)
    #pragma unroll
    for (int j = 0; j < 4; ++j)
      acc[i][j] = (f32x4)0.0f;

  const int arow  = tid >> 1;
  const int ahalf = (tid & 1) * 16;
  const int kb4 = (tid >> 5) * 4;
  const int cb4 = (tid & 31) * 4;

  for (int kt = 0; kt < nkt; ++kt) {
    const int k0 = kt * 32;
    __syncthreads();
    {
      const f32x4* p = (const f32x4*)(X + (size_t)(m0 + arow) * P_DIM + k0 + ahalf);
      f32x4 v0 = p[0], v1 = p[1], v2 = p[2], v3 = p[3];
      u16x8 w0, w1;
      #pragma unroll
      for (int i = 0; i < 4; ++i) {
        w0[i] = f2bf(v0[i]); w0[i + 4] = f2bf(v1[i]);
        w1[i] = f2bf(v2[i]); w1[i + 4] = f2bf(v3[i]);
      }
      *(u16x8*)&Alds[arow * LDT + ahalf]     = w0;
      *(u16x8*)&Alds[arow * LDT + ahalf + 8] = w1;
    }
    {
      float e[4][4];
      #pragma unroll
      for (int i = 0; i < 4; ++i) {
        f32x4 r = *(const f32x4*)(Theta + (size_t)(k0 + kb4 + i) * P_DIM + c0 + cb4);
        #pragma unroll
        for (int j = 0; j < 4; ++j)
          e[i][j] = ((k0 + kb4 + i) < (c0 + cb4 + j)) ? r[j] : 0.0f;
      }
      #pragma unroll
      for (int j = 0; j < 4; ++j) {
        u16x4 wv;
        #pragma unroll
        for (int i = 0; i < 4; ++i) wv[i] = f2bf(e[i][j]);
        *(u16x4*)&Blds[(cb4 + j) * LDT + kb4] = wv;
      }
    }
    __syncthreads();

    bf16x8 af[4], bfr[4];
    #pragma unroll
    for (int mi = 0; mi < 4; ++mi) {
      u16x8 t = *(const u16x8*)&Alds[(wm * 64 + mi * 16 + l15) * LDT + lg * 8];
      af[mi] = __builtin_bit_cast(bf16x8, t);
    }
    #pragma unroll
    for (int ni = 0; ni < 4; ++ni) {
      u16x8 t = *(const u16x8*)&Blds[(wn * 64 + ni * 16 + l15) * LDT + lg * 8];
      bfr[ni] = __builtin_bit_cast(bf16x8, t);
    }
    #pragma unroll
    for (int mi = 0; mi < 4; ++mi)
      #pragma unroll
      for (int ni = 0; ni < 4; ++ni)
        acc[mi][ni] = __builtin_amdgcn_mfma_f32_16x16x32_bf16(af[mi], bfr[ni], acc[mi][ni], 0, 0, 0);
  }

  float ysum[4][4];
  #pragma unroll
  for (int mi = 0; mi < 4; ++mi)
    #pragma unroll
    for (int r = 0; r < 4; ++r)
      ysum[mi][r] = 0.0f;

  #pragma unroll
  for (int ni = 0; ni < 4; ++ni) {
    const int col = c0 + wn * 64 + ni * 16 + l15;
    const float bta = beta[col];
    #pragma unroll
    for (int mi = 0; mi < 4; ++mi) {
      const int rowb = m0 + wm * 64 + mi * 16 + lg * 4;
      #pragma unroll
      for (int r = 0; r < 4; ++r) {
        float xv = X[(size_t)(rowb + r) * P_DIM + col];
        ysum[mi][r] += (acc[mi][ni][r] + bta) * xv;
      }
    }
  }

  #pragma unroll
  for (int m = 1; m < 16; m <<= 1)
    #pragma unroll
    for (int mi = 0; mi < 4; ++mi)
      #pragma unroll
      for (int r = 0; r < 4; ++r)
        ysum[mi][r] += __shfl_xor(ysum[mi][r], m);

  if (l15 == 0) {
    #pragma unroll
    for (int mi = 0; mi < 4; ++mi)
      #pragma unroll
      for (int r = 0; r < 4; ++r)
        atomicAdd(&y[m0 + wm * 64 + mi * 16 + lg * 4 + r], ysum[mi][r]);
  }
}

extern "C" void kernel_launch(void* const* d_in, const int* in_sizes, int n_in,
                              void* d_out, int out_size, void* d_ws, size_t ws_size,
                              hipStream_t stream) {
  const float* X     = (const float*)d_in[0];
  const float* beta0 = (const float*)d_in[1];
  const float* beta  = (const float*)d_in[2];
  const float* Theta = (const float*)d_in[3];
  float* y = (float*)d_out;

  const size_t need = (size_t)P_DIM * P_DIM * 2;   // only Tt (2 MB)
  if (ws_size >= need) {
    u16* Tt = (u16*)d_ws;
    conv_theta<<<dim3(32, 32), 128, 0, stream>>>(Theta, Tt, y, beta0);
    gemm_r14<<<(N_ROWS / BM) * (P_DIM / BN), 512, 0, stream>>>(X, Tt, beta, y);
  } else {
    init_y<<<N_ROWS / 256, 256, 0, stream>>>(y, beta0);
    fused_quad_fallback<<<(N_ROWS / 128) * (P_DIM / 128), 256, 0, stream>>>(X, beta, Theta, y);
  }
}